// Round 2
// baseline (14148.862 us; speedup 1.0000x reference)
//
#include <hip/hip_runtime.h>

// LSTM_50208167690847 v2: 2-layer BiLSTM (B=256,T=512,IN=64,H=256) + FC.
// Design: LDS-resident weight slices (16-way gate-column split per direction x
// batch-group), per-step cross-block h exchange via L2/IF with device-scope
// flag barrier. fp16 MFMA 16x16x32, f32 accum. Layer-1 input projection folded
// into the scan (K=768) -> no xg1 buffer. Layer-1 backward = single step (tail).
// Workspace: ~131.6 MB.

#define B_ 256
#define T_ 512
#define IN_ 64
#define H_ 256

typedef __attribute__((ext_vector_type(8))) _Float16 f16x8;
typedef __attribute__((ext_vector_type(4))) _Float16 f16x4;
typedef __attribute__((ext_vector_type(4))) float f32x4;

__device__ __forceinline__ float sigm(float x){ return 1.f/(1.f+__expf(-x)); }
__device__ __forceinline__ float tanh_(float x){ return 1.f - 2.f/(__expf(2.f*x)+1.f); }

// pack weights into per-(dir,colblock) MFMA-B fragment order:
// flat = (((dir*16+q)*4 + gt)*KT + kt)*512 + lane*8 + e
// gate col g = gt*256 + q*16 + (lane&15); k = kt*32 + (lane>>4)*8 + e
// src: k < KX -> ih[(dir*1024+g)*KX + k] ; else hh[(dir*1024+g)*KH + (k-KX)]
__global__ void pack_w(const float* __restrict__ ih, const float* __restrict__ hh,
                       _Float16* __restrict__ dst, int KX, int KH, int KT, int total) {
    int idx = blockIdx.x * 256 + threadIdx.x;
    if (idx >= total) return;
    int e = idx & 7, lane = (idx >> 3) & 63;
    int rest = idx >> 9;
    int kt = rest % KT;
    int r  = rest / KT;
    int gt = r & 3;
    int qd = r >> 2;
    int q = qd & 15, dir = qd >> 4;
    int g = gt * 256 + q * 16 + (lane & 15);
    int k = kt * 32 + (lane >> 4) * 8 + e;
    float v = (k < KX) ? ih[(size_t)(dir * 1024 + g) * KX + k]
                       : hh[(size_t)(dir * 1024 + g) * KH + (k - KX)];
    dst[idx] = (_Float16)v;
}

// Recurrent scan. Block = (grp, q): grp = batch-group (x direction for L0),
// q = gate-column block (owns h-cols [q*16, q*16+16), all 4 gates).
// 16 col-blocks per group sync per step via cnt[grp*T+s].
template <int KXT, int KHT, int MROWS, bool L0>
__global__ __launch_bounds__(MROWS * 16)
void lstm_scan(const float* __restrict__ x, const _Float16* __restrict__ xin,
               const _Float16* __restrict__ wpack, const float* __restrict__ bias,
               _Float16* __restrict__ hbuf, unsigned int* __restrict__ cnt,
               _Float16* __restrict__ out0, float* __restrict__ hlast) {
    constexpr int KT = KXT + KHT;
    constexpr int KX = KXT * 32;
    constexpr int KP = KT * 32 + 8;          // LDS A stride: 2-way alias = free
    constexpr int NTHR = MROWS * 16;
    constexpr int MT = MROWS / 16;
    constexpr int WB = 4 * KT * 512;         // w_lds element count

    extern __shared__ char smem[];
    _Float16* w_lds = (_Float16*)smem;
    _Float16* a_lds = (_Float16*)(smem + (size_t)WB * 2);
    float*    g_lds = (float*)(smem + (size_t)WB * 2 + (size_t)MROWS * KP * 2);

    const int tid = threadIdx.x, lane = tid & 63, wave = tid >> 6;
    const int q   = blockIdx.x & 15;
    const int grp = blockIdx.x >> 4;
    const int dir = L0 ? (grp >> 3) : 0;
    const int b0r = L0 ? ((grp & 7) * MROWS) : (grp * MROWS);
    const int mh = wave & (MT - 1);
    const int gt = wave / MT;

    // stage weight slice into LDS (once)
    {
        const f16x8* wsrc = (const f16x8*)(wpack + (size_t)(L0 ? (dir * 16 + q) : q) * WB);
        f16x8* wdst = (f16x8*)w_lds;
        for (int i = tid; i < WB / 8; i += NTHR) wdst[i] = wsrc[i];
    }
    // zero h-region of a_lds (h0 = 0)
    {
        f16x8 z;
#pragma unroll
        for (int e = 0; e < 8; ++e) z[e] = (_Float16)0.f;
#pragma unroll
        for (int j = 0; j < 2; ++j) {
            int ch = j * NTHR + tid;             // MROWS*32 chunks total
            int qs = ch / (MROWS * 2);
            int wi = ch % (MROWS * 2);
            int hr = wi >> 1, hc = (wi & 1) * 8;
            *(f16x8*)&a_lds[(size_t)hr * KP + KX + qs * 16 + hc] = z;
        }
    }

    const int row = tid >> 4, col = tid & 15;
    const float bI = bias[dir * 1024 +       q * 16 + col];
    const float bF = bias[dir * 1024 + 256 + q * 16 + col];
    const float bG = bias[dir * 1024 + 512 + q * 16 + col];
    const float bO = bias[dir * 1024 + 768 + q * 16 + col];
    float c_reg = 0.f;

    // x staging: t0 direct into LDS; prefetch t1 into regs
    const int xrow = tid >> 4;
    float4 xv;                       // L0 prefetch
    f16x8 xp0, xp1, xp2, xp3;        // L1 prefetch
    {
        int t0 = dir ? (T_ - 1) : 0;
        int t1 = dir ? (T_ - 2) : 1;
        if constexpr (L0) {
            const int c4 = (tid & 15) * 4;
            float4 v0 = *(const float4*)&x[((size_t)(b0r + xrow) * T_ + t0) * IN_ + c4];
            f16x4 h4; h4[0]=(_Float16)v0.x; h4[1]=(_Float16)v0.y; h4[2]=(_Float16)v0.z; h4[3]=(_Float16)v0.w;
            *(f16x4*)&a_lds[(size_t)xrow * KP + c4] = h4;
            xv = *(const float4*)&x[((size_t)(b0r + xrow) * T_ + t1) * IN_ + c4];
        } else {
#pragma unroll
            for (int j = 0; j < 4; ++j) {
                int ch = j * NTHR + tid;
                int r2 = ch >> 6, c8 = (ch & 63) * 8;
                f16x8 v = *(const f16x8*)&xin[((size_t)(b0r + r2) * T_ + t0) * 512 + c8];
                *(f16x8*)&a_lds[(size_t)r2 * KP + c8] = v;
            }
#pragma unroll
            for (int j = 0; j < 4; ++j) {
                int ch = j * NTHR + tid;
                int r2 = ch >> 6, c8 = (ch & 63) * 8;
                f16x8 v = *(const f16x8*)&xin[((size_t)(b0r + r2) * T_ + t1) * 512 + c8];
                if (j == 0) xp0 = v; else if (j == 1) xp1 = v; else if (j == 2) xp2 = v; else xp3 = v;
            }
        }
    }

    for (int s = 0; s < T_; ++s) {
        const int t = dir ? (T_ - 1 - s) : s;
        if (s > 0) {
            if (tid == 0) {
                while (__hip_atomic_load(&cnt[grp * T_ + (s - 1)], __ATOMIC_RELAXED,
                                         __HIP_MEMORY_SCOPE_AGENT) < 16u)
                    __builtin_amdgcn_s_sleep(1);
                __threadfence();   // acquire: invalidate stale L1/L2 before h loads
            }
            __syncthreads();                                       // B1
            const _Float16* hg = hbuf + (size_t)(grp * 2 + ((s - 1) & 1)) * 16 * (MROWS * 16);
#pragma unroll
            for (int j = 0; j < 2; ++j) {
                int ch = j * NTHR + tid;
                int qs = ch / (MROWS * 2);
                int wi = ch % (MROWS * 2);
                int hr = wi >> 1, hc = (wi & 1) * 8;
                f16x8 v = *(const f16x8*)&hg[(size_t)qs * (MROWS * 16) + hr * 16 + hc];
                *(f16x8*)&a_lds[(size_t)hr * KP + KX + qs * 16 + hc] = v;
            }
        }
        __syncthreads();                                           // B2

        // GEMM: [MROWS, K] @ [K, 64] ; wave tile (mh, gate gt) 16x16, 2 acc chains
        const int arow = mh * 16 + (lane & 15);
        const int kc8 = (lane >> 4) * 8;
        f32x4 acc0 = {0.f, 0.f, 0.f, 0.f}, acc1 = {0.f, 0.f, 0.f, 0.f};
#pragma unroll
        for (int kt = 0; kt < KT; kt += 2) {
            f16x8 a0 = *(const f16x8*)&a_lds[(size_t)arow * KP + kt * 32 + kc8];
            f16x8 b0v = *(const f16x8*)&w_lds[((size_t)(gt * KT + kt) * 64 + lane) * 8];
            acc0 = __builtin_amdgcn_mfma_f32_16x16x32_f16(a0, b0v, acc0, 0, 0, 0);
            f16x8 a1 = *(const f16x8*)&a_lds[(size_t)arow * KP + (kt + 1) * 32 + kc8];
            f16x8 b1v = *(const f16x8*)&w_lds[((size_t)(gt * KT + kt + 1) * 64 + lane) * 8];
            acc1 = __builtin_amdgcn_mfma_f32_16x16x32_f16(a1, b1v, acc1, 0, 0, 0);
        }
        f32x4 acc = acc0 + acc1;
        {
            const int crow = mh * 16 + (lane >> 4) * 4, ccol = lane & 15;
#pragma unroll
            for (int qq = 0; qq < 4; ++qq)
                g_lds[(size_t)(gt * MROWS + crow + qq) * 16 + ccol] = acc[qq];
        }
        __syncthreads();                                           // B3

        // stage x(s+1) from regs; prefetch x(s+2)
        {
            int sn2 = (s + 2 < T_) ? s + 2 : T_ - 1;
            int t2 = dir ? (T_ - 1 - sn2) : sn2;
            if constexpr (L0) {
                const int c4 = (tid & 15) * 4;
                f16x4 h4; h4[0]=(_Float16)xv.x; h4[1]=(_Float16)xv.y; h4[2]=(_Float16)xv.z; h4[3]=(_Float16)xv.w;
                *(f16x4*)&a_lds[(size_t)xrow * KP + c4] = h4;
                xv = *(const float4*)&x[((size_t)(b0r + xrow) * T_ + t2) * IN_ + c4];
            } else {
#pragma unroll
                for (int j = 0; j < 4; ++j) {
                    int ch = j * NTHR + tid;
                    int r2 = ch >> 6, c8 = (ch & 63) * 8;
                    f16x8 v = (j == 0) ? xp0 : ((j == 1) ? xp1 : ((j == 2) ? xp2 : xp3));
                    *(f16x8*)&a_lds[(size_t)r2 * KP + c8] = v;
                }
#pragma unroll
                for (int j = 0; j < 4; ++j) {
                    int ch = j * NTHR + tid;
                    int r2 = ch >> 6, c8 = (ch & 63) * 8;
                    f16x8 v = *(const f16x8*)&xin[((size_t)(b0r + r2) * T_ + t2) * 512 + c8];
                    if (j == 0) xp0 = v; else if (j == 1) xp1 = v; else if (j == 2) xp2 = v; else xp3 = v;
                }
            }
        }

        // elementwise gate math (thread owns (row, hcol q*16+col); c in reg)
        {
            float gI = g_lds[(size_t)(0 * MROWS + row) * 16 + col] + bI;
            float gF = g_lds[(size_t)(1 * MROWS + row) * 16 + col] + bF;
            float gG = g_lds[(size_t)(2 * MROWS + row) * 16 + col] + bG;
            float gO = g_lds[(size_t)(3 * MROWS + row) * 16 + col] + bO;
            float i_ = sigm(gI), f_ = sigm(gF), g2 = tanh_(gG), o_ = sigm(gO);
            c_reg = f_ * c_reg + i_ * g2;
            float h = o_ * tanh_(c_reg);
            _Float16 hf = (_Float16)h;
            hbuf[(size_t)((grp * 2 + (s & 1)) * 16 + q) * (MROWS * 16) + row * 16 + col] = hf;
            if constexpr (L0) {
                out0[((size_t)(b0r + row) * T_ + t) * 512 + dir * 256 + q * 16 + col] = hf;
            } else {
                if (s == T_ - 1) hlast[(size_t)(b0r + row) * 256 + q * 16 + col] = h;
            }
        }
        __syncthreads();                                           // B4 (drains stores)
        if (tid == 0)
            __hip_atomic_fetch_add(&cnt[grp * T_ + s], 1u, __ATOMIC_RELEASE,
                                   __HIP_MEMORY_SCOPE_AGENT);
    }
}

// layer1 backward single step (t=T-1, zero state) + FC over [h1f | hb]
__global__ __launch_bounds__(256)
void tail_kernel(const _Float16* __restrict__ out0, const float* __restrict__ Wih1,
                 const float* __restrict__ b1, const float* __restrict__ fcw,
                 const float* __restrict__ fcb, const float* __restrict__ h1f,
                 float* __restrict__ out) {
    const int b = blockIdx.x, tid = threadIdx.x;
    __shared__ float xs[512];
    __shared__ float red[256];
    for (int i = tid; i < 512; i += 256)
        xs[i] = (float)out0[((size_t)b * T_ + (T_ - 1)) * 512 + i];
    __syncthreads();
    const float* Wb = Wih1 + (size_t)1024 * 512;  // dir 1
    const float* wI = Wb + (size_t)tid * 512;
    const float* wG = Wb + (size_t)(512 + tid) * 512;
    const float* wO = Wb + (size_t)(768 + tid) * 512;
    float aI = 0.f, aG = 0.f, aO = 0.f;
    for (int k = 0; k < 512; k += 4) {
        float4 xv = *(const float4*)&xs[k];
        float4 w0 = *(const float4*)&wI[k];
        float4 w1 = *(const float4*)&wG[k];
        float4 w2 = *(const float4*)&wO[k];
        aI += xv.x * w0.x + xv.y * w0.y + xv.z * w0.z + xv.w * w0.w;
        aG += xv.x * w1.x + xv.y * w1.y + xv.z * w1.z + xv.w * w1.w;
        aO += xv.x * w2.x + xv.y * w2.y + xv.z * w2.z + xv.w * w2.w;
    }
    float i_ = sigm(aI + b1[1024 + tid]);
    float g_ = tanh_(aG + b1[1024 + 512 + tid]);
    float o_ = sigm(aO + b1[1024 + 768 + tid]);
    float c = i_ * g_;  // c0 = 0
    float hb = o_ * tanh_(c);
    float part = h1f[b * 256 + tid] * fcw[tid] + hb * fcw[256 + tid];
    red[tid] = part;
    __syncthreads();
    for (int sx = 128; sx > 0; sx >>= 1) {
        if (tid < sx) red[tid] += red[tid + sx];
        __syncthreads();
    }
    if (tid == 0) out[b] = red[0] + fcb[0];
}

extern "C" void kernel_launch(void* const* d_in, const int* in_sizes, int n_in,
                              void* d_out, int out_size, void* d_ws, size_t ws_size,
                              hipStream_t stream) {
    const float* x    = (const float*)d_in[0];
    const float* Wih0 = (const float*)d_in[1];
    const float* Whh0 = (const float*)d_in[2];
    const float* b0   = (const float*)d_in[3];
    const float* Wih1 = (const float*)d_in[4];
    const float* Whh1 = (const float*)d_in[5];
    const float* b1   = (const float*)d_in[6];
    const float* fcw  = (const float*)d_in[7];
    const float* fcb  = (const float*)d_in[8];

    char* ws = (char*)d_ws;
    _Float16* W0pack   = (_Float16*)(ws + 0);           // 1,310,720 B
    _Float16* W1pack   = (_Float16*)(ws + 1310720);     // 1,572,864 B
    unsigned int* cnt0 = (unsigned int*)(ws + 2883584); // 32,768 B
    unsigned int* cnt1 = (unsigned int*)(ws + 2916352); // 32,768 B
    _Float16* hbuf     = (_Float16*)(ws + 2949120);     // 524,288 B
    float* h1f         = (float*)(ws + 3473408);        // 262,144 B
    _Float16* out0     = (_Float16*)(ws + 3735552);     // 134,217,728 B -> end 137,953,280

    hipMemsetAsync(ws + 2883584, 0, 65536, stream);     // zero both cnt arrays

    hipLaunchKernelGGL(pack_w, dim3(2560), dim3(256), 0, stream,
                       Wih0, Whh0, W0pack, 64, 256, 10, 655360);
    hipLaunchKernelGGL(pack_w, dim3(3072), dim3(256), 0, stream,
                       Wih1, Whh1, W1pack, 512, 256, 24, 786432);

    hipFuncSetAttribute((const void*)(lstm_scan<2, 8, 32, true>),
                        hipFuncAttributeMaxDynamicSharedMemorySize, 70144);
    hipFuncSetAttribute((const void*)(lstm_scan<16, 8, 16, false>),
                        hipFuncAttributeMaxDynamicSharedMemorySize, 127232);

    // L0: 2 dir x 8 batch-groups(M=32) x 16 col-blocks = 256 blocks (co-resident)
    hipLaunchKernelGGL((lstm_scan<2, 8, 32, true>), dim3(256), dim3(512), 70144, stream,
                       x, (const _Float16*)nullptr, W0pack, b0, hbuf, cnt0,
                       out0, (float*)nullptr);
    // L1 fwd: 16 batch-groups(M=16) x 16 col-blocks = 256 blocks, K=768 folded
    hipLaunchKernelGGL((lstm_scan<16, 8, 16, false>), dim3(256), dim3(256), 127232, stream,
                       (const float*)nullptr, (const _Float16*)out0, W1pack, b1, hbuf, cnt1,
                       (_Float16*)nullptr, h1f);
    hipLaunchKernelGGL(tail_kernel, dim3(256), dim3(256), 0, stream,
                       out0, Wih1, b1, fcw, fcb, h1f, (float*)d_out);
}

// Round 3
// 4699.062 us; speedup vs baseline: 3.0110x; 3.0110x over previous
//
#include <hip/hip_runtime.h>

// LSTM_50208167690847 v3: 2-layer BiLSTM (B=256,T=512,IN=64,H=256) + FC.
// v2 -> v3: replace fence-based (buffer_wbl2/inv) cross-block sync with
// fine-grained coherent (relaxed agent-scope, sc0sc1) h/flag traffic:
//  - producers: relaxed atomic h stores -> s_waitcnt vmcnt(0) -> barrier -> seq flag
//  - consumers: 16-lane flag poll -> h loaded straight into MFMA A-fragments
// x-part MFMAs hoisted before the poll (independent of h).

#define B_ 256
#define T_ 512
#define IN_ 64
#define H_ 256

typedef __attribute__((ext_vector_type(8))) _Float16 f16x8;
typedef __attribute__((ext_vector_type(4))) _Float16 f16x4;
typedef __attribute__((ext_vector_type(4))) float f32x4;

__device__ __forceinline__ float sigm(float x){ return 1.f/(1.f+__expf(-x)); }
__device__ __forceinline__ float tanh_(float x){ return 1.f - 2.f/(__expf(2.f*x)+1.f); }

// pack weights into per-(dir,colblock) MFMA-B fragment order:
// flat = (((dir*16+q)*4 + gt)*KT + kt)*512 + lane*8 + e
// gate col g = gt*256 + q*16 + (lane&15); k = kt*32 + (lane>>4)*8 + e
__global__ void pack_w(const float* __restrict__ ih, const float* __restrict__ hh,
                       _Float16* __restrict__ dst, int KX, int KH, int KT, int total) {
    int idx = blockIdx.x * 256 + threadIdx.x;
    if (idx >= total) return;
    int e = idx & 7, lane = (idx >> 3) & 63;
    int rest = idx >> 9;
    int kt = rest % KT;
    int r  = rest / KT;
    int gt = r & 3;
    int qd = r >> 2;
    int q = qd & 15, dir = qd >> 4;
    int g = gt * 256 + q * 16 + (lane & 15);
    int k = kt * 32 + (lane >> 4) * 8 + e;
    float v = (k < KX) ? ih[(size_t)(dir * 1024 + g) * KX + k]
                       : hh[(size_t)(dir * 1024 + g) * KH + (k - KX)];
    dst[idx] = (_Float16)v;
}

// Block = (q, grp): blockIdx.x = q*16 + grp (peers of a group land on the same
// XCD under round-robin dispatch; correctness does not depend on it).
template <int KXT, int KHT, int MROWS, bool L0>
__global__ __launch_bounds__(MROWS * 16)
void lstm_scan(const float* __restrict__ x, const _Float16* __restrict__ xin,
               const _Float16* __restrict__ wpack, const float* __restrict__ bias,
               _Float16* __restrict__ hbuf, unsigned int* __restrict__ flags,
               _Float16* __restrict__ out0, float* __restrict__ hlast) {
    constexpr int KT = KXT + KHT;
    constexpr int KX = KXT * 32;
    constexpr int KP = KT * 32 + 8;          // LDS A stride (16B-aligned rows)
    constexpr int NTHR = MROWS * 16;
    constexpr int MT = MROWS / 16;
    constexpr int WB = 4 * KT * 512;         // w_lds element count

    extern __shared__ char smem[];
    _Float16* w_lds = (_Float16*)smem;
    _Float16* a_lds = (_Float16*)(smem + (size_t)WB * 2);
    float*    g_lds = (float*)(smem + (size_t)WB * 2 + (size_t)MROWS * KP * 2);

    const int tid = threadIdx.x, lane = tid & 63, wave = tid >> 6;
    const int q   = blockIdx.x >> 4;
    const int grp = blockIdx.x & 15;
    const int dir = L0 ? (grp >> 3) : 0;
    const int b0r = L0 ? ((grp & 7) * MROWS) : (grp * MROWS);
    const int mh = wave & (MT - 1);
    const int gt = wave / MT;

    // stage weight slice into LDS (once)
    {
        const f16x8* wsrc = (const f16x8*)(wpack + (size_t)(L0 ? (dir * 16 + q) : q) * WB);
        f16x8* wdst = (f16x8*)w_lds;
        for (int i = tid; i < WB / 8; i += NTHR) wdst[i] = wsrc[i];
    }

    const int row = tid >> 4, col = tid & 15;
    const float bI = bias[dir * 1024 +       q * 16 + col];
    const float bF = bias[dir * 1024 + 256 + q * 16 + col];
    const float bG = bias[dir * 1024 + 512 + q * 16 + col];
    const float bO = bias[dir * 1024 + 768 + q * 16 + col];
    float c_reg = 0.f;

    // x staging: t0 direct into LDS; prefetch t1 into regs
    const int xrow = tid >> 4;
    float4 xv;                        // L0 prefetch
    f16x8 xp0, xp1, xp2, xp3;         // L1 prefetch
    {
        int t0 = dir ? (T_ - 1) : 0;
        int t1 = dir ? (T_ - 2) : 1;
        if constexpr (L0) {
            const int c4 = (tid & 15) * 4;
            float4 v0 = *(const float4*)&x[((size_t)(b0r + xrow) * T_ + t0) * IN_ + c4];
            f16x4 h4; h4[0]=(_Float16)v0.x; h4[1]=(_Float16)v0.y; h4[2]=(_Float16)v0.z; h4[3]=(_Float16)v0.w;
            *(f16x4*)&a_lds[(size_t)xrow * KP + c4] = h4;
            xv = *(const float4*)&x[((size_t)(b0r + xrow) * T_ + t1) * IN_ + c4];
        } else {
#pragma unroll
            for (int j = 0; j < 4; ++j) {
                int ch = j * NTHR + tid;
                int r2 = ch >> 6, c8 = (ch & 63) * 8;
                f16x8 v = *(const f16x8*)&xin[((size_t)(b0r + r2) * T_ + t0) * 512 + c8];
                *(f16x8*)&a_lds[(size_t)r2 * KP + c8] = v;
            }
#pragma unroll
            for (int j = 0; j < 4; ++j) {
                int ch = j * NTHR + tid;
                int r2 = ch >> 6, c8 = (ch & 63) * 8;
                f16x8 v = *(const f16x8*)&xin[((size_t)(b0r + r2) * T_ + t1) * 512 + c8];
                if (j == 0) xp0 = v; else if (j == 1) xp1 = v; else if (j == 2) xp2 = v; else xp3 = v;
            }
        }
    }
    __syncthreads();

    const int arow = mh * 16 + (lane & 15);
    const int kc8 = (lane >> 4) * 8;

    for (int s = 0; s < T_; ++s) {
        const int t = dir ? (T_ - 1 - s) : s;

        // ---- phase A: x-part MFMAs (independent of peers' h) ----
        f32x4 acc0 = {0.f,0.f,0.f,0.f}, acc1 = {0.f,0.f,0.f,0.f};
#pragma unroll
        for (int kt = 0; kt < KXT; ++kt) {
            f16x8 a = *(const f16x8*)&a_lds[(size_t)arow * KP + kt * 32 + kc8];
            f16x8 b = *(const f16x8*)&w_lds[((size_t)(gt * KT + kt) * 64 + lane) * 8];
            if (kt & 1) acc1 = __builtin_amdgcn_mfma_f32_16x16x32_f16(a, b, acc1, 0, 0, 0);
            else        acc0 = __builtin_amdgcn_mfma_f32_16x16x32_f16(a, b, acc0, 0, 0, 0);
        }

        // ---- phase B: wait for peers' h(s-1), load straight into A-frags ----
        if (s > 0) {
            if (lane < 16) {
                unsigned int* fp = (unsigned int*)&flags[grp * 16 + lane];
                while (__hip_atomic_load(fp, __ATOMIC_RELAXED, __HIP_MEMORY_SCOPE_AGENT)
                       < (unsigned)s) {}
            }
            asm volatile("" ::: "memory");
            const _Float16* hg = hbuf + ((size_t)grp * 2 + ((s - 1) & 1)) * (MROWS * 256);
            const unsigned long long* hq = (const unsigned long long*)hg;
            f16x8 hf[KHT];
#pragma unroll
            for (int kt = 0; kt < KHT; ++kt) {
                int off4 = (arow * 256 + kt * 32 + kc8) >> 2;
                unsigned long long u0 = __hip_atomic_load(
                    (unsigned long long*)&hq[off4], __ATOMIC_RELAXED, __HIP_MEMORY_SCOPE_AGENT);
                unsigned long long u1 = __hip_atomic_load(
                    (unsigned long long*)&hq[off4 + 1], __ATOMIC_RELAXED, __HIP_MEMORY_SCOPE_AGENT);
                union { unsigned long long u[2]; f16x8 v; } cv;
                cv.u[0] = u0; cv.u[1] = u1;
                hf[kt] = cv.v;
            }
#pragma unroll
            for (int kt = 0; kt < KHT; ++kt) {
                f16x8 b = *(const f16x8*)&w_lds[((size_t)(gt * KT + KXT + kt) * 64 + lane) * 8];
                if (kt & 1) acc1 = __builtin_amdgcn_mfma_f32_16x16x32_f16(hf[kt], b, acc1, 0, 0, 0);
                else        acc0 = __builtin_amdgcn_mfma_f32_16x16x32_f16(hf[kt], b, acc0, 0, 0, 0);
            }
        }
        f32x4 acc = acc0 + acc1;
        {
            const int crow = mh * 16 + (lane >> 4) * 4, ccol = lane & 15;
#pragma unroll
            for (int qq = 0; qq < 4; ++qq)
                g_lds[(size_t)(gt * MROWS + crow + qq) * 17 + ccol] = acc[qq];
        }
        __syncthreads();                       // B3: gates ready; a_lds reads done

        // ---- phase D: elementwise; publish h via relaxed coherent stores ----
        {
            float gI = g_lds[(size_t)(0 * MROWS + row) * 17 + col] + bI;
            float gF = g_lds[(size_t)(1 * MROWS + row) * 17 + col] + bF;
            float gG = g_lds[(size_t)(2 * MROWS + row) * 17 + col] + bG;
            float gO = g_lds[(size_t)(3 * MROWS + row) * 17 + col] + bO;
            float i_ = sigm(gI), f_ = sigm(gF), g2 = tanh_(gG), o_ = sigm(gO);
            c_reg = f_ * c_reg + i_ * g2;
            float h = o_ * tanh_(c_reg);
            union { _Float16 h; unsigned short u; } hb; hb.h = (_Float16)h;
            unsigned int ov = (unsigned int)__shfl_xor((int)hb.u, 1);
            if (!(lane & 1)) {
                unsigned int word = (unsigned int)hb.u | ((ov & 0xFFFFu) << 16);
                size_t eo = (((size_t)grp * 2 + (s & 1)) * MROWS + row) * 256 + q * 16 + col;
                __hip_atomic_store((unsigned int*)(hbuf + eo), word,
                                   __ATOMIC_RELAXED, __HIP_MEMORY_SCOPE_AGENT);
            }
            if constexpr (L0) {
                out0[((size_t)(b0r + row) * T_ + t) * 512 + dir * 256 + q * 16 + col] = hb.h;
            } else {
                if (s == T_ - 1)
                    hlast[(size_t)(b0r + row) * 256 + q * 16 + col] = h;
            }
        }

        // ---- phase E: stage x(s+1) from regs ----
        if constexpr (L0) {
            const int c4 = (tid & 15) * 4;
            f16x4 h4; h4[0]=(_Float16)xv.x; h4[1]=(_Float16)xv.y; h4[2]=(_Float16)xv.z; h4[3]=(_Float16)xv.w;
            *(f16x4*)&a_lds[(size_t)xrow * KP + c4] = h4;
        } else {
#pragma unroll
            for (int j = 0; j < 4; ++j) {
                int ch = j * NTHR + tid;
                int r2 = ch >> 6, c8 = (ch & 63) * 8;
                f16x8 v = (j == 0) ? xp0 : ((j == 1) ? xp1 : ((j == 2) ? xp2 : xp3));
                *(f16x8*)&a_lds[(size_t)r2 * KP + c8] = v;
            }
        }

        asm volatile("s_waitcnt vmcnt(0)" ::: "memory");   // h stores ack'd (this wave)
        __syncthreads();                                   // all waves ack'd + x staged
        if (tid == 0)
            __hip_atomic_store((unsigned int*)&flags[grp * 16 + q], (unsigned int)(s + 1),
                               __ATOMIC_RELAXED, __HIP_MEMORY_SCOPE_AGENT);

        // ---- prefetch x(s+2) (completes long before next phase E) ----
        {
            int sn2 = (s + 2 < T_) ? s + 2 : T_ - 1;
            int t2 = dir ? (T_ - 1 - sn2) : sn2;
            if constexpr (L0) {
                const int c4 = (tid & 15) * 4;
                xv = *(const float4*)&x[((size_t)(b0r + xrow) * T_ + t2) * IN_ + c4];
            } else {
#pragma unroll
                for (int j = 0; j < 4; ++j) {
                    int ch = j * NTHR + tid;
                    int r2 = ch >> 6, c8 = (ch & 63) * 8;
                    f16x8 v = *(const f16x8*)&xin[((size_t)(b0r + r2) * T_ + t2) * 512 + c8];
                    if (j == 0) xp0 = v; else if (j == 1) xp1 = v; else if (j == 2) xp2 = v; else xp3 = v;
                }
            }
        }
    }
}

// layer1 backward single step (t=T-1, zero state) + FC over [h1f | hb]
__global__ __launch_bounds__(256)
void tail_kernel(const _Float16* __restrict__ out0, const float* __restrict__ Wih1,
                 const float* __restrict__ b1, const float* __restrict__ fcw,
                 const float* __restrict__ fcb, const float* __restrict__ h1f,
                 float* __restrict__ out) {
    const int b = blockIdx.x, tid = threadIdx.x;
    __shared__ float xs[512];
    __shared__ float red[256];
    for (int i = tid; i < 512; i += 256)
        xs[i] = (float)out0[((size_t)b * T_ + (T_ - 1)) * 512 + i];
    __syncthreads();
    const float* Wb = Wih1 + (size_t)1024 * 512;  // dir 1
    const float* wI = Wb + (size_t)tid * 512;
    const float* wG = Wb + (size_t)(512 + tid) * 512;
    const float* wO = Wb + (size_t)(768 + tid) * 512;
    float aI = 0.f, aG = 0.f, aO = 0.f;
    for (int k = 0; k < 512; k += 4) {
        float4 xv = *(const float4*)&xs[k];
        float4 w0 = *(const float4*)&wI[k];
        float4 w1 = *(const float4*)&wG[k];
        float4 w2 = *(const float4*)&wO[k];
        aI += xv.x * w0.x + xv.y * w0.y + xv.z * w0.z + xv.w * w0.w;
        aG += xv.x * w1.x + xv.y * w1.y + xv.z * w1.z + xv.w * w1.w;
        aO += xv.x * w2.x + xv.y * w2.y + xv.z * w2.z + xv.w * w2.w;
    }
    float i_ = sigm(aI + b1[1024 + tid]);
    float g_ = tanh_(aG + b1[1024 + 512 + tid]);
    float o_ = sigm(aO + b1[1024 + 768 + tid]);
    float c = i_ * g_;  // c0 = 0
    float hb = o_ * tanh_(c);
    float part = h1f[b * 256 + tid] * fcw[tid] + hb * fcw[256 + tid];
    red[tid] = part;
    __syncthreads();
    for (int sx = 128; sx > 0; sx >>= 1) {
        if (tid < sx) red[tid] += red[tid + sx];
        __syncthreads();
    }
    if (tid == 0) out[b] = red[0] + fcb[0];
}

extern "C" void kernel_launch(void* const* d_in, const int* in_sizes, int n_in,
                              void* d_out, int out_size, void* d_ws, size_t ws_size,
                              hipStream_t stream) {
    const float* x    = (const float*)d_in[0];
    const float* Wih0 = (const float*)d_in[1];
    const float* Whh0 = (const float*)d_in[2];
    const float* b0   = (const float*)d_in[3];
    const float* Wih1 = (const float*)d_in[4];
    const float* Whh1 = (const float*)d_in[5];
    const float* b1   = (const float*)d_in[6];
    const float* fcw  = (const float*)d_in[7];
    const float* fcb  = (const float*)d_in[8];

    char* ws = (char*)d_ws;
    _Float16* W0pack    = (_Float16*)(ws + 0);           // 1,310,720 B
    _Float16* W1pack    = (_Float16*)(ws + 1310720);     // 1,572,864 B -> 2,883,584
    unsigned int* flg0  = (unsigned int*)(ws + 2883584); // 1,024 B
    unsigned int* flg1  = (unsigned int*)(ws + 2887680); // 1,024 B
    _Float16* hbuf0     = (_Float16*)(ws + 2891776);     // 524,288 B
    _Float16* hbuf1     = (_Float16*)(ws + 3416064);     // 262,144 B
    float* h1f          = (float*)(ws + 3678208);        // 262,144 B
    _Float16* out0      = (_Float16*)(ws + 3940352);     // 134,217,728 B -> ~138.2 MB

    hipMemsetAsync(ws + 2883584, 0, 8192, stream);       // zero both flag arrays

    hipLaunchKernelGGL(pack_w, dim3(2560), dim3(256), 0, stream,
                       Wih0, Whh0, W0pack, 64, 256, 10, 655360);
    hipLaunchKernelGGL(pack_w, dim3(3072), dim3(256), 0, stream,
                       Wih1, Whh1, W1pack, 512, 256, 24, 786432);

    hipFuncSetAttribute((const void*)(lstm_scan<2, 8, 32, true>),
                        hipFuncAttributeMaxDynamicSharedMemorySize, 70656);
    hipFuncSetAttribute((const void*)(lstm_scan<16, 8, 16, false>),
                        hipFuncAttributeMaxDynamicSharedMemorySize, 127488);

    // L0: 16 groups (2 dir x 8 bg, M=32) x 16 col-blocks = 256 blocks
    hipLaunchKernelGGL((lstm_scan<2, 8, 32, true>), dim3(256), dim3(512), 70656, stream,
                       x, (const _Float16*)nullptr, W0pack, b0, hbuf0, flg0,
                       out0, (float*)nullptr);
    // L1 fwd: 16 groups (M=16) x 16 col-blocks = 256 blocks, K=768 folded
    hipLaunchKernelGGL((lstm_scan<16, 8, 16, false>), dim3(256), dim3(256), 127488, stream,
                       (const float*)nullptr, (const _Float16*)out0, W1pack, b1, hbuf1, flg1,
                       (_Float16*)nullptr, h1f);
    hipLaunchKernelGGL(tail_kernel, dim3(256), dim3(256), 0, stream,
                       out0, Wih1, b1, fcw, fcb, h1f, (float*)d_out);
}

// Round 5
// 3700.963 us; speedup vs baseline: 3.8230x; 1.2697x over previous
//
#include <hip/hip_runtime.h>

// LSTM_50208167690847 v5: 2-layer BiLSTM (B=256,T=512,IN=64,H=256) + FC.
// v3 -> v5 (v4's placement games abandoned after HW hang):
//  - cooperative LDS h-gather (block loads h once; waves read frags from LDS)
//    instead of per-wave redundant coherent loads: 4x exchange-volume cut
//  - L0 column split widened to 8-way (80KB weight slice, 2 N-subtiles/wave):
//    halves q-duplication (16MB -> 2MB per step of fabric atomics)
//  - out0 store + x prefetch moved after flag publish (off the vmcnt drain)
//  - sync primitives identical to v3 (proven): relaxed agent atomics,
//    vmcnt(0) + barrier + monotonic flag, parity double-buffered hbuf.

#define T_ 512
#define IN_ 64
#define H_ 256

typedef __attribute__((ext_vector_type(8))) _Float16 f16x8;
typedef __attribute__((ext_vector_type(4))) _Float16 f16x4;
typedef __attribute__((ext_vector_type(4))) float f32x4;

__device__ __forceinline__ float sigm(float x){ return 1.f/(1.f+__expf(-x)); }
__device__ __forceinline__ float tanh_(float x){ return 1.f - 2.f/(__expf(2.f*x)+1.f); }

// pack weights into per-(dir,q) MFMA-B fragment order:
// flat = ((((dir*NQ+q)*4 + gt)*NSUB + sub)*KT + kt)*512 + lane*8 + e
// gate col g = gt*256 + q*QW + sub*16 + (lane&15); k = kt*32 + (lane>>4)*8 + e
__global__ void pack_w(const float* __restrict__ ih, const float* __restrict__ hh,
                       _Float16* __restrict__ dst, int KX, int KH, int KT,
                       int QW, int NSUB, int NQ, int total) {
    int idx = blockIdx.x * 256 + threadIdx.x;
    if (idx >= total) return;
    int e = idx & 7, lane = (idx >> 3) & 63;
    int u = idx >> 9;
    int kt = u % KT; u /= KT;
    int sub = u % NSUB; u /= NSUB;
    int gt = u & 3; u >>= 2;
    int q = u % NQ; int dir = u / NQ;
    int g = gt * 256 + q * QW + sub * 16 + (lane & 15);
    int k = kt * 32 + (lane >> 4) * 8 + e;
    float v = (k < KX) ? ih[(size_t)(dir * 1024 + g) * KX + k]
                       : hh[(size_t)(dir * 1024 + g) * KH + (k - KX)];
    dst[idx] = (_Float16)v;
}

template <int KXT, int KHT, int MROWS, int QW, bool IS_L0>
__global__ __launch_bounds__(MROWS * 16)
void lstm_scan(const float* __restrict__ x, const _Float16* __restrict__ xin,
               const _Float16* __restrict__ wpack, const float* __restrict__ bias,
               _Float16* __restrict__ hbuf, unsigned int* __restrict__ flags,
               _Float16* __restrict__ out0, float* __restrict__ hlast) {
    constexpr int KT = KXT + KHT, KX = KXT * 32;
    constexpr int NTHR = MROWS * 16, MT = MROWS / 16;
    constexpr int NSUB = QW / 16, NQ = 256 / QW;
    constexpr int WBE = 4 * NSUB * KT * 512;   // weight slice elems
    constexpr int KP = KX + 8, HP = 256 + 8, GP = QW + 1;

    extern __shared__ char smem[];
    _Float16* w_lds = (_Float16*)smem;
    _Float16* h_lds = (_Float16*)(smem + (size_t)WBE * 2);
    _Float16* a_lds = (_Float16*)(smem + (size_t)WBE * 2 + MROWS * HP * 2);
    float*    g_lds = (float*)(smem + (size_t)WBE * 2 + MROWS * HP * 2 + MROWS * KP * 2);

    const int tid = threadIdx.x, lane = tid & 63, wave = tid >> 6;
    const int q = blockIdx.x % NQ, grp = blockIdx.x / NQ;
    const int dir = IS_L0 ? (grp >> 3) : 0;
    const int b0r = (IS_L0 ? (grp & 7) : grp) * MROWS;
    const int mh = wave & (MT - 1), gt = wave / MT;

    // stage weight slice into LDS (once)
    {
        const f16x8* src = (const f16x8*)(wpack + (size_t)(dir * NQ + q) * WBE);
        f16x8* dst = (f16x8*)w_lds;
        for (int i = tid; i < WBE / 8; i += NTHR) dst[i] = src[i];
    }

    // elementwise mapping: thread -> (row erow, NSUB cols at q*QW + ecp*NSUB)
    const int erow = tid >> 4, ecp = tid & 15;
    float b_[4][NSUB], c_reg[NSUB];
#pragma unroll
    for (int g4 = 0; g4 < 4; ++g4)
#pragma unroll
        for (int j = 0; j < NSUB; ++j)
            b_[g4][j] = bias[dir * 1024 + g4 * 256 + q * QW + ecp * NSUB + j];
#pragma unroll
    for (int j = 0; j < NSUB; ++j) c_reg[j] = 0.f;

    // x staging: t0 into a_lds, t1 prefetched to regs
    float4 xv;            // L0
    f16x8 xp[4];          // L1
    {
        int t0 = dir ? (T_ - 1) : 0;
        int t1 = dir ? (T_ - 2) : 1;
        if constexpr (IS_L0) {
            const int xrow = tid >> 4, c4 = (tid & 15) * 4;
            float4 v0 = *(const float4*)&x[((size_t)(b0r + xrow) * T_ + t0) * IN_ + c4];
            f16x4 h4; h4[0]=(_Float16)v0.x; h4[1]=(_Float16)v0.y; h4[2]=(_Float16)v0.z; h4[3]=(_Float16)v0.w;
            *(f16x4*)&a_lds[(size_t)xrow * KP + c4] = h4;
            xv = *(const float4*)&x[((size_t)(b0r + xrow) * T_ + t1) * IN_ + c4];
        } else {
#pragma unroll
            for (int j = 0; j < 4; ++j) {
                int ch = j * NTHR + tid;
                int r2 = ch >> 6, c8 = (ch & 63) * 8;
                f16x8 v = *(const f16x8*)&xin[((size_t)(b0r + r2) * T_ + t0) * 512 + c8];
                *(f16x8*)&a_lds[(size_t)r2 * KP + c8] = v;
            }
#pragma unroll
            for (int j = 0; j < 4; ++j) {
                int ch = j * NTHR + tid;
                int r2 = ch >> 6, c8 = (ch & 63) * 8;
                xp[j] = *(const f16x8*)&xin[((size_t)(b0r + r2) * T_ + t1) * 512 + c8];
            }
        }
    }
    __syncthreads();

    const int arow = mh * 16 + (lane & 15);
    const int kc8 = (lane >> 4) * 8;

    for (int s = 0; s < T_; ++s) {
        const int t = dir ? (T_ - 1 - s) : s;

        // ---- phase A: x-part MFMAs (independent of peers' h) ----
        f32x4 acc[NSUB][2];
#pragma unroll
        for (int sub = 0; sub < NSUB; ++sub) {
            f32x4 z = {0.f, 0.f, 0.f, 0.f};
            acc[sub][0] = z; acc[sub][1] = z;
        }
#pragma unroll
        for (int kt = 0; kt < KXT; ++kt) {
            f16x8 a = *(const f16x8*)&a_lds[(size_t)arow * KP + kt * 32 + kc8];
#pragma unroll
            for (int sub = 0; sub < NSUB; ++sub) {
                f16x8 b = *(const f16x8*)&w_lds[(((size_t)(gt * NSUB + sub) * KT + kt) * 64 + lane) * 8];
                acc[sub][kt & 1] = __builtin_amdgcn_mfma_f32_16x16x32_f16(a, b, acc[sub][kt & 1], 0, 0, 0);
            }
        }

        // ---- phase B: poll peers' flags; cooperative h gather -> LDS ----
        if (s > 0) {
            if (lane < NQ) {
                unsigned int* fp = flags + grp * NQ + lane;
                while (__hip_atomic_load(fp, __ATOMIC_RELAXED, __HIP_MEMORY_SCOPE_AGENT)
                       < (unsigned)s) {}
            }
            asm volatile("" ::: "memory");
            unsigned long long* hq = (unsigned long long*)
                (hbuf + ((size_t)grp * 2 + ((s - 1) & 1)) * (MROWS * 256));
            unsigned long long hv[4];
#pragma unroll
            for (int i = 0; i < 4; ++i)
                hv[i] = __hip_atomic_load(&hq[i * NTHR + tid], __ATOMIC_RELAXED,
                                          __HIP_MEMORY_SCOPE_AGENT);
#pragma unroll
            for (int i = 0; i < 4; ++i) {
                int u = i * NTHR + tid;
                int hr = u >> 6, cq = u & 63;
                union { unsigned long long u64; f16x4 v; } cv; cv.u64 = hv[i];
                *(f16x4*)&h_lds[(size_t)hr * HP + cq * 4] = cv.v;
            }
        }
        __syncthreads();   // B_h: h_lds ready; all phase-A a_lds reads done

        // stage x(s+1) into a_lds (from prefetch regs)
        if constexpr (IS_L0) {
            const int xrow = tid >> 4, c4 = (tid & 15) * 4;
            f16x4 h4; h4[0]=(_Float16)xv.x; h4[1]=(_Float16)xv.y; h4[2]=(_Float16)xv.z; h4[3]=(_Float16)xv.w;
            *(f16x4*)&a_lds[(size_t)xrow * KP + c4] = h4;
        } else {
#pragma unroll
            for (int j = 0; j < 4; ++j) {
                int ch = j * NTHR + tid;
                int r2 = ch >> 6, c8 = (ch & 63) * 8;
                *(f16x8*)&a_lds[(size_t)r2 * KP + c8] = xp[j];
            }
        }

        // ---- phase C: h-part MFMAs from LDS ----
        if (s > 0) {
#pragma unroll
            for (int kt = 0; kt < KHT; ++kt) {
                f16x8 a = *(const f16x8*)&h_lds[(size_t)arow * HP + kt * 32 + kc8];
#pragma unroll
                for (int sub = 0; sub < NSUB; ++sub) {
                    f16x8 b = *(const f16x8*)&w_lds[(((size_t)(gt * NSUB + sub) * KT + KXT + kt) * 64 + lane) * 8];
                    acc[sub][kt & 1] = __builtin_amdgcn_mfma_f32_16x16x32_f16(a, b, acc[sub][kt & 1], 0, 0, 0);
                }
            }
        }
        {
            const int crow = mh * 16 + (lane >> 4) * 4, ccol = lane & 15;
#pragma unroll
            for (int sub = 0; sub < NSUB; ++sub) {
                f32x4 av = acc[sub][0] + acc[sub][1];
#pragma unroll
                for (int qq = 0; qq < 4; ++qq)
                    g_lds[(size_t)(gt * MROWS + crow + qq) * GP + sub * 16 + ccol] = av[qq];
            }
        }
        __syncthreads();   // B_g: gates ready

        // ---- phase D: elementwise; publish h (relaxed agent atomics) ----
        float hval[NSUB];
        {
#pragma unroll
            for (int j = 0; j < NSUB; ++j) {
                float gI = g_lds[(size_t)(0 * MROWS + erow) * GP + ecp * NSUB + j] + b_[0][j];
                float gF = g_lds[(size_t)(1 * MROWS + erow) * GP + ecp * NSUB + j] + b_[1][j];
                float gG = g_lds[(size_t)(2 * MROWS + erow) * GP + ecp * NSUB + j] + b_[2][j];
                float gO = g_lds[(size_t)(3 * MROWS + erow) * GP + ecp * NSUB + j] + b_[3][j];
                float i_ = sigm(gI), f_ = sigm(gF), g2 = tanh_(gG), o_ = sigm(gO);
                c_reg[j] = f_ * c_reg[j] + i_ * g2;
                hval[j] = o_ * tanh_(c_reg[j]);
            }
            size_t pbase = ((size_t)grp * 2 + (s & 1)) * (MROWS * 256);
            if constexpr (NSUB == 2) {
                union { _Float16 h[2]; unsigned int w; } pk;
                pk.h[0] = (_Float16)hval[0]; pk.h[1] = (_Float16)hval[1];
                __hip_atomic_store((unsigned int*)(hbuf + pbase + (size_t)erow * 256 + q * QW + ecp * 2),
                                   pk.w, __ATOMIC_RELAXED, __HIP_MEMORY_SCOPE_AGENT);
            } else {
                union { _Float16 h; unsigned short u; } hb; hb.h = (_Float16)hval[0];
                unsigned int ov = (unsigned int)__shfl_xor((int)hb.u, 1);
                if (!(lane & 1)) {
                    unsigned int word = (unsigned int)hb.u | ((ov & 0xFFFFu) << 16);
                    __hip_atomic_store((unsigned int*)(hbuf + pbase + (size_t)erow * 256 + q * QW + ecp),
                                       word, __ATOMIC_RELAXED, __HIP_MEMORY_SCOPE_AGENT);
                }
            }
        }

        asm volatile("s_waitcnt vmcnt(0)" ::: "memory");  // h publishes ack'd (this wave)
        __syncthreads();                                  // B_p: all waves ack'd
        if (tid == 0)
            __hip_atomic_store(flags + grp * NQ + q, (unsigned int)(s + 1),
                               __ATOMIC_RELAXED, __HIP_MEMORY_SCOPE_AGENT);

        // ---- post-publish (off critical path): out0/hlast + x prefetch ----
        if constexpr (IS_L0) {
            union { _Float16 h[2]; unsigned int w; } pk;
            pk.h[0] = (_Float16)hval[0]; pk.h[1] = (_Float16)hval[1];
            *(unsigned int*)&out0[((size_t)(b0r + erow) * T_ + t) * 512 + dir * 256 + q * QW + ecp * 2] = pk.w;
        } else {
            if (s == T_ - 1)
                hlast[(size_t)(b0r + erow) * 256 + q * QW + ecp] = hval[0];
        }
        {
            int sn2 = (s + 2 < T_) ? s + 2 : T_ - 1;
            int t2 = dir ? (T_ - 1 - sn2) : sn2;
            if constexpr (IS_L0) {
                const int xrow = tid >> 4, c4 = (tid & 15) * 4;
                xv = *(const float4*)&x[((size_t)(b0r + xrow) * T_ + t2) * IN_ + c4];
            } else {
#pragma unroll
                for (int j = 0; j < 4; ++j) {
                    int ch = j * NTHR + tid;
                    int r2 = ch >> 6, c8 = (ch & 63) * 8;
                    xp[j] = *(const f16x8*)&xin[((size_t)(b0r + r2) * T_ + t2) * 512 + c8];
                }
            }
        }
    }
}

// layer1 backward single step (t=T-1, zero state) + FC over [h1f | hb]
__global__ __launch_bounds__(256)
void tail_kernel(const _Float16* __restrict__ out0, const float* __restrict__ Wih1,
                 const float* __restrict__ b1, const float* __restrict__ fcw,
                 const float* __restrict__ fcb, const float* __restrict__ h1f,
                 float* __restrict__ out) {
    const int b = blockIdx.x, tid = threadIdx.x;
    __shared__ float xs[512];
    __shared__ float red[256];
    for (int i = tid; i < 512; i += 256)
        xs[i] = (float)out0[((size_t)b * T_ + (T_ - 1)) * 512 + i];
    __syncthreads();
    const float* Wb = Wih1 + (size_t)1024 * 512;  // dir 1
    const float* wI = Wb + (size_t)tid * 512;
    const float* wG = Wb + (size_t)(512 + tid) * 512;
    const float* wO = Wb + (size_t)(768 + tid) * 512;
    float aI = 0.f, aG = 0.f, aO = 0.f;
    for (int k = 0; k < 512; k += 4) {
        float4 xv = *(const float4*)&xs[k];
        float4 w0 = *(const float4*)&wI[k];
        float4 w1 = *(const float4*)&wG[k];
        float4 w2 = *(const float4*)&wO[k];
        aI += xv.x * w0.x + xv.y * w0.y + xv.z * w0.z + xv.w * w0.w;
        aG += xv.x * w1.x + xv.y * w1.y + xv.z * w1.z + xv.w * w1.w;
        aO += xv.x * w2.x + xv.y * w2.y + xv.z * w2.z + xv.w * w2.w;
    }
    float i_ = sigm(aI + b1[1024 + tid]);
    float g_ = tanh_(aG + b1[1024 + 512 + tid]);
    float o_ = sigm(aO + b1[1024 + 768 + tid]);
    float c = i_ * g_;  // c0 = 0
    float hb = o_ * tanh_(c);
    float part = h1f[b * 256 + tid] * fcw[tid] + hb * fcw[256 + tid];
    red[tid] = part;
    __syncthreads();
    for (int sx = 128; sx > 0; sx >>= 1) {
        if (tid < sx) red[tid] += red[tid + sx];
        __syncthreads();
    }
    if (tid == 0) out[b] = red[0] + fcb[0];
}

extern "C" void kernel_launch(void* const* d_in, const int* in_sizes, int n_in,
                              void* d_out, int out_size, void* d_ws, size_t ws_size,
                              hipStream_t stream) {
    const float* x    = (const float*)d_in[0];
    const float* Wih0 = (const float*)d_in[1];
    const float* Whh0 = (const float*)d_in[2];
    const float* b0   = (const float*)d_in[3];
    const float* Wih1 = (const float*)d_in[4];
    const float* Whh1 = (const float*)d_in[5];
    const float* b1   = (const float*)d_in[6];
    const float* fcw  = (const float*)d_in[7];
    const float* fcb  = (const float*)d_in[8];

    char* ws = (char*)d_ws;
    _Float16* W0pack   = (_Float16*)(ws + 0);           // 1,310,720 B
    _Float16* W1pack   = (_Float16*)(ws + 1310720);     // 1,572,864 B -> 2,883,584
    unsigned int* flg0 = (unsigned int*)(ws + 2883584); // 512 B used
    unsigned int* flg1 = (unsigned int*)(ws + 2884608); // 1,024 B
    _Float16* hbuf0    = (_Float16*)(ws + 2885632);     // 524,288 B -> 3,409,920
    _Float16* hbuf1    = (_Float16*)(ws + 3409920);     // 262,144 B -> 3,672,064
    float* h1f         = (float*)(ws + 3672064);        // 262,144 B -> 3,934,208
    _Float16* out0     = (_Float16*)(ws + 3934208);     // 134,217,728 B -> ~138.2 MB

    hipMemsetAsync(ws + 2883584, 0, 2048, stream);      // zero both flag arrays

    // L0: QW=32, NSUB=2, NQ=8, KT=10, dirs=2 -> 655360 elems
    hipLaunchKernelGGL(pack_w, dim3(2560), dim3(256), 0, stream,
                       Wih0, Whh0, W0pack, 64, 256, 10, 32, 2, 8, 655360);
    // L1: QW=16, NSUB=1, NQ=16, KT=24, dirs=1 -> 786432 elems
    hipLaunchKernelGGL(pack_w, dim3(3072), dim3(256), 0, stream,
                       Wih1, Whh1, W1pack, 512, 256, 24, 16, 1, 16, 786432);

    // L0 LDS: 81920(w) + 16896(h) + 4608(a) + 16896(g) = 120320 (>80KB -> 1 blk/CU)
    hipFuncSetAttribute((const void*)(lstm_scan<2, 8, 32, 32, true>),
                        hipFuncAttributeMaxDynamicSharedMemorySize, 120320);
    // L1 LDS: 98304(w) + 8448(h) + 16640(a) + 4352(g) = 127744
    hipFuncSetAttribute((const void*)(lstm_scan<16, 8, 16, 16, false>),
                        hipFuncAttributeMaxDynamicSharedMemorySize, 127744);

    // L0: 16 groups (2 dir x 8 bg, M=32) x 8 col-blocks = 128 blocks
    hipLaunchKernelGGL((lstm_scan<2, 8, 32, 32, true>), dim3(128), dim3(512), 120320, stream,
                       x, (const _Float16*)nullptr, W0pack, b0, hbuf0, flg0,
                       out0, (float*)nullptr);
    // L1 fwd: 16 groups (M=16) x 16 col-blocks = 256 blocks, K=768 folded
    hipLaunchKernelGGL((lstm_scan<16, 8, 16, 16, false>), dim3(256), dim3(256), 127744, stream,
                       (const float*)nullptr, (const _Float16*)out0, W1pack, b1, hbuf1, flg1,
                       (_Float16*)nullptr, h1f);
    hipLaunchKernelGGL(tail_kernel, dim3(256), dim3(256), 0, stream,
                       out0, Wih1, b1, fcw, fcb, h1f, (float*)d_out);
}

// Round 7
// 2793.686 us; speedup vs baseline: 5.0646x; 1.3248x over previous
//
#include <hip/hip_runtime.h>

// LSTM_50208167690847 v7: 2-layer BiLSTM (B=256,T=512,IN=64,H=256) + FC.
// v5 -> v7: tagged-u64 data-poll exchange (proven fabric atomics only).
// Each h-pair is published as one atomic u64 {tag=step, 2xf16}; consumers
// poll the data words directly until tag matches. This fuses v5's three
// serial fabric RTTs (store-ack, flag-detect, h-load) into ONE:
//   - publish: fire-and-forget relaxed agent u64 atomic store (no vmcnt/flag)
//   - gather:  relaxed agent u64 atomic loads, retry words with stale tags
// Correctness: publish of h_s data-depends (via barriers+LDS+MFMA) on the
// full gather of h_{s-1}, so seeing all peers' tag==s implies the old buffer
// is fully consumed -> 2-buffer parity reuse is race-free; u64 atomicity
// keeps tag+payload untorn; 0xFF memset per launch kills replay staleness.
// Block map: grp = bid % 16 -> group peers same-XCD (L2-flavor ready).

#define T_ 512
#define IN_ 64
#define H_ 256

typedef __attribute__((ext_vector_type(8))) _Float16 f16x8;
typedef __attribute__((ext_vector_type(4))) _Float16 f16x4;
typedef __attribute__((ext_vector_type(4))) float f32x4;
typedef unsigned long long u64;
typedef unsigned int u32;

__device__ __forceinline__ float sigm(float x){ return 1.f/(1.f+__expf(-x)); }
__device__ __forceinline__ float tanh_(float x){ return 1.f - 2.f/(__expf(2.f*x)+1.f); }

// pack weights into per-(dir,q) MFMA-B fragment order:
// flat = ((((dir*NQ+q)*4 + gt)*NSUB + sub)*KT + kt)*512 + lane*8 + e
// gate col g = gt*256 + q*QW + sub*16 + (lane&15); k = kt*32 + (lane>>4)*8 + e
__global__ void pack_w(const float* __restrict__ ih, const float* __restrict__ hh,
                       _Float16* __restrict__ dst, int KX, int KH, int KT,
                       int QW, int NSUB, int NQ, int total) {
    int idx = blockIdx.x * 256 + threadIdx.x;
    if (idx >= total) return;
    int e = idx & 7, lane = (idx >> 3) & 63;
    int u = idx >> 9;
    int kt = u % KT; u /= KT;
    int sub = u % NSUB; u /= NSUB;
    int gt = u & 3; u >>= 2;
    int q = u % NQ; int dir = u / NQ;
    int g = gt * 256 + q * QW + sub * 16 + (lane & 15);
    int k = kt * 32 + (lane >> 4) * 8 + e;
    float v = (k < KX) ? ih[(size_t)(dir * 1024 + g) * KX + k]
                       : hh[(size_t)(dir * 1024 + g) * KH + (k - KX)];
    dst[idx] = (_Float16)v;
}

// Block map: grp = blockIdx.x % 16, q = blockIdx.x / 16.
template <int KXT, int KHT, int MROWS, int QW, bool IS_L0>
__global__ __launch_bounds__(MROWS * 16)
void lstm_scan(const float* __restrict__ x, const _Float16* __restrict__ xin,
               const _Float16* __restrict__ wpack, const float* __restrict__ bias,
               u64* __restrict__ hbuf,
               _Float16* __restrict__ out0, float* __restrict__ hlast) {
    constexpr int KT = KXT + KHT, KX = KXT * 32;
    constexpr int NTHR = MROWS * 16, MT = MROWS / 16;
    constexpr int NSUB = QW / 16, NQ = 256 / QW;
    constexpr int WBE = 4 * NSUB * KT * 512;   // weight slice elems
    constexpr int KP = KX + 8;                  // a_lds f16 row stride
    constexpr int HPW = 132;                    // h_lds u32 row stride (16B-aligned rows)
    constexpr int GP = QW + 1;
    constexpr int NWORD = MROWS * 128;          // u64 words per group-buffer
    constexpr int NW = NWORD / NTHR;            // words per thread (= 8)

    extern __shared__ char smem[];
    _Float16* w_lds = (_Float16*)smem;
    u32*      h32   = (u32*)(smem + (size_t)WBE * 2);
    _Float16* a_lds = (_Float16*)(smem + (size_t)WBE * 2 + (size_t)MROWS * HPW * 4);
    float*    g_lds = (float*)(smem + (size_t)WBE * 2 + (size_t)MROWS * HPW * 4
                               + (size_t)MROWS * KP * 2);

    const int tid = threadIdx.x, lane = tid & 63, wave = tid >> 6;
    const int grp = blockIdx.x & 15, q = blockIdx.x >> 4;
    const int dir = IS_L0 ? (grp >> 3) : 0;
    const int b0r = (IS_L0 ? (grp & 7) : grp) * MROWS;
    const int mh = wave & (MT - 1), gt = wave / MT;

    // stage weight slice into LDS (once)
    {
        const f16x8* src = (const f16x8*)(wpack + (size_t)(dir * NQ + q) * WBE);
        f16x8* dst = (f16x8*)w_lds;
        for (int i = tid; i < WBE / 8; i += NTHR) dst[i] = src[i];
    }

    // elementwise mapping: thread -> (row erow, NSUB cols at q*QW + ecp*NSUB)
    const int erow = tid >> 4, ecp = tid & 15;
    float b_[4][NSUB], c_reg[NSUB];
#pragma unroll
    for (int g4 = 0; g4 < 4; ++g4)
#pragma unroll
        for (int j = 0; j < NSUB; ++j)
            b_[g4][j] = bias[dir * 1024 + g4 * 256 + q * QW + ecp * NSUB + j];
#pragma unroll
    for (int j = 0; j < NSUB; ++j) c_reg[j] = 0.f;

    // x staging: t0 into a_lds, t1 prefetched to regs
    float4 xv;            // L0
    f16x8 xp[4];          // L1
    {
        int t0 = dir ? (T_ - 1) : 0;
        int t1 = dir ? (T_ - 2) : 1;
        if constexpr (IS_L0) {
            const int xrow = tid >> 4, c4 = (tid & 15) * 4;
            float4 v0 = *(const float4*)&x[((size_t)(b0r + xrow) * T_ + t0) * IN_ + c4];
            f16x4 h4; h4[0]=(_Float16)v0.x; h4[1]=(_Float16)v0.y; h4[2]=(_Float16)v0.z; h4[3]=(_Float16)v0.w;
            *(f16x4*)&a_lds[(size_t)xrow * KP + c4] = h4;
            xv = *(const float4*)&x[((size_t)(b0r + xrow) * T_ + t1) * IN_ + c4];
        } else {
#pragma unroll
            for (int j = 0; j < 4; ++j) {
                int ch = j * NTHR + tid;
                int r2 = ch >> 6, c8 = (ch & 63) * 8;
                f16x8 v = *(const f16x8*)&xin[((size_t)(b0r + r2) * T_ + t0) * 512 + c8];
                *(f16x8*)&a_lds[(size_t)r2 * KP + c8] = v;
            }
#pragma unroll
            for (int j = 0; j < 4; ++j) {
                int ch = j * NTHR + tid;
                int r2 = ch >> 6, c8 = (ch & 63) * 8;
                xp[j] = *(const f16x8*)&xin[((size_t)(b0r + r2) * T_ + t1) * 512 + c8];
            }
        }
    }
    __syncthreads();

    const int arow = mh * 16 + (lane & 15);
    const int kc8 = (lane >> 4) * 8;     // f16 offset; u32 offset = (lane>>4)*4

    for (int s = 0; s < T_; ++s) {
        const int t = dir ? (T_ - 1 - s) : s;

        // ---- phase A: x-part MFMAs (independent of peers' h) ----
        f32x4 acc[NSUB][2];
#pragma unroll
        for (int sub = 0; sub < NSUB; ++sub) {
            f32x4 z = {0.f, 0.f, 0.f, 0.f};
            acc[sub][0] = z; acc[sub][1] = z;
        }
#pragma unroll
        for (int kt = 0; kt < KXT; ++kt) {
            f16x8 a = *(const f16x8*)&a_lds[(size_t)arow * KP + kt * 32 + kc8];
#pragma unroll
            for (int sub = 0; sub < NSUB; ++sub) {
                f16x8 b = *(const f16x8*)&w_lds[(((size_t)(gt * NSUB + sub) * KT + kt) * 64 + lane) * 8];
                acc[sub][kt & 1] = __builtin_amdgcn_mfma_f32_16x16x32_f16(a, b, acc[sub][kt & 1], 0, 0, 0);
            }
        }

        // ---- phase B: tagged data-poll gather of h(s-1) -> h_lds ----
        if (s > 0) {
            const u32 want = (u32)(s - 1);
            u64* bw = hbuf + ((size_t)grp * 2 + ((s - 1) & 1)) * NWORD;
            u64 got[NW];
#pragma unroll
            for (int k = 0; k < NW; ++k)
                got[k] = __hip_atomic_load(&bw[k * NTHR + tid], __ATOMIC_RELAXED,
                                           __HIP_MEMORY_SCOPE_AGENT);
            for (;;) {
                bool ok = true;
#pragma unroll
                for (int k = 0; k < NW; ++k) ok &= ((u32)(got[k] >> 32) == want);
                if (ok) break;
#pragma unroll
                for (int k = 0; k < NW; ++k)
                    if ((u32)(got[k] >> 32) != want)
                        got[k] = __hip_atomic_load(&bw[k * NTHR + tid], __ATOMIC_RELAXED,
                                                   __HIP_MEMORY_SCOPE_AGENT);
            }
#pragma unroll
            for (int k = 0; k < NW; ++k) {
                int w = k * NTHR + tid;
                h32[(size_t)(w >> 7) * HPW + (w & 127)] = (u32)got[k];
            }
        }
        __syncthreads();   // B1: h_lds ready; phase-A a_lds reads done

        // stage x(s+1) into a_lds (from prefetch regs)
        if constexpr (IS_L0) {
            const int xrow = tid >> 4, c4 = (tid & 15) * 4;
            f16x4 h4; h4[0]=(_Float16)xv.x; h4[1]=(_Float16)xv.y; h4[2]=(_Float16)xv.z; h4[3]=(_Float16)xv.w;
            *(f16x4*)&a_lds[(size_t)xrow * KP + c4] = h4;
        } else {
#pragma unroll
            for (int j = 0; j < 4; ++j) {
                int ch = j * NTHR + tid;
                int r2 = ch >> 6, c8 = (ch & 63) * 8;
                *(f16x8*)&a_lds[(size_t)r2 * KP + c8] = xp[j];
            }
        }

        // ---- phase C: h-part MFMAs from h_lds ----
        if (s > 0) {
#pragma unroll
            for (int kt = 0; kt < KHT; ++kt) {
                f16x8 a = *(const f16x8*)&h32[(size_t)arow * HPW + kt * 16 + (lane >> 4) * 4];
#pragma unroll
                for (int sub = 0; sub < NSUB; ++sub) {
                    f16x8 b = *(const f16x8*)&w_lds[(((size_t)(gt * NSUB + sub) * KT + KXT + kt) * 64 + lane) * 8];
                    acc[sub][kt & 1] = __builtin_amdgcn_mfma_f32_16x16x32_f16(a, b, acc[sub][kt & 1], 0, 0, 0);
                }
            }
        }
        {
            const int crow = mh * 16 + (lane >> 4) * 4, ccol = lane & 15;
#pragma unroll
            for (int sub = 0; sub < NSUB; ++sub) {
                f32x4 av = acc[sub][0] + acc[sub][1];
#pragma unroll
                for (int qq = 0; qq < 4; ++qq)
                    g_lds[(size_t)(gt * MROWS + crow + qq) * GP + sub * 16 + ccol] = av[qq];
            }
        }
        __syncthreads();   // B2: gates ready; a_lds staged for next step

        // ---- phase D: elementwise; tagged publish (fire-and-forget) ----
        float hval[NSUB];
#pragma unroll
        for (int j = 0; j < NSUB; ++j) {
            float gI = g_lds[(size_t)(0 * MROWS + erow) * GP + ecp * NSUB + j] + b_[0][j];
            float gF = g_lds[(size_t)(1 * MROWS + erow) * GP + ecp * NSUB + j] + b_[1][j];
            float gG = g_lds[(size_t)(2 * MROWS + erow) * GP + ecp * NSUB + j] + b_[2][j];
            float gO = g_lds[(size_t)(3 * MROWS + erow) * GP + ecp * NSUB + j] + b_[3][j];
            float i_ = sigm(gI), f_ = sigm(gF), g2 = tanh_(gG), o_ = sigm(gO);
            c_reg[j] = f_ * c_reg[j] + i_ * g2;
            hval[j] = o_ * tanh_(c_reg[j]);
        }
        {
            u64* bw = hbuf + ((size_t)grp * 2 + (s & 1)) * NWORD;
            if constexpr (NSUB == 2) {
                union { _Float16 h[2]; u32 u; } pk;
                pk.h[0] = (_Float16)hval[0]; pk.h[1] = (_Float16)hval[1];
                u64 word = (u64)pk.u | ((u64)(u32)s << 32);
                __hip_atomic_store(&bw[erow * 128 + q * 16 + ecp], word,
                                   __ATOMIC_RELAXED, __HIP_MEMORY_SCOPE_AGENT);
            } else {
                union { _Float16 h; unsigned short u; } hb; hb.h = (_Float16)hval[0];
                u32 ov = (u32)__shfl_xor((int)hb.u, 1);
                if (!(lane & 1)) {
                    u32 lo = (u32)hb.u | ((ov & 0xFFFFu) << 16);
                    u64 word = (u64)lo | ((u64)(u32)s << 32);
                    __hip_atomic_store(&bw[erow * 128 + ((q * 16 + ecp) >> 1)], word,
                                       __ATOMIC_RELAXED, __HIP_MEMORY_SCOPE_AGENT);
                }
            }
        }

        // ---- post-publish (off critical path): out0/hlast + x prefetch ----
        if constexpr (IS_L0) {
            union { _Float16 h[2]; u32 w; } pk;
            pk.h[0] = (_Float16)hval[0]; pk.h[1] = (_Float16)hval[1];
            *(u32*)&out0[((size_t)(b0r + erow) * T_ + t) * 512 + dir * 256 + q * QW + ecp * 2] = pk.w;
        } else {
            if (s == T_ - 1)
                hlast[(size_t)(b0r + erow) * 256 + q * QW + ecp] = hval[0];
        }
        {
            int sn2 = (s + 2 < T_) ? s + 2 : T_ - 1;
            int t2 = dir ? (T_ - 1 - sn2) : sn2;
            if constexpr (IS_L0) {
                const int xrow = tid >> 4, c4 = (tid & 15) * 4;
                xv = *(const float4*)&x[((size_t)(b0r + xrow) * T_ + t2) * IN_ + c4];
            } else {
#pragma unroll
                for (int j = 0; j < 4; ++j) {
                    int ch = j * NTHR + tid;
                    int r2 = ch >> 6, c8 = (ch & 63) * 8;
                    xp[j] = *(const f16x8*)&xin[((size_t)(b0r + r2) * T_ + t2) * 512 + c8];
                }
            }
        }
        // no end-of-step barrier needed: a racing wave's next gather
        // self-synchronizes on the data tags; g_lds/a_lds protected by B1/B2.
    }
}

// layer1 backward single step (t=T-1, zero state) + FC over [h1f | hb]
__global__ __launch_bounds__(256)
void tail_kernel(const _Float16* __restrict__ out0, const float* __restrict__ Wih1,
                 const float* __restrict__ b1, const float* __restrict__ fcw,
                 const float* __restrict__ fcb, const float* __restrict__ h1f,
                 float* __restrict__ out) {
    const int b = blockIdx.x, tid = threadIdx.x;
    __shared__ float xs[512];
    __shared__ float red[256];
    for (int i = tid; i < 512; i += 256)
        xs[i] = (float)out0[((size_t)b * T_ + (T_ - 1)) * 512 + i];
    __syncthreads();
    const float* Wb = Wih1 + (size_t)1024 * 512;  // dir 1
    const float* wI = Wb + (size_t)tid * 512;
    const float* wG = Wb + (size_t)(512 + tid) * 512;
    const float* wO = Wb + (size_t)(768 + tid) * 512;
    float aI = 0.f, aG = 0.f, aO = 0.f;
    for (int k = 0; k < 512; k += 4) {
        float4 xv = *(const float4*)&xs[k];
        float4 w0 = *(const float4*)&wI[k];
        float4 w1 = *(const float4*)&wG[k];
        float4 w2 = *(const float4*)&wO[k];
        aI += xv.x * w0.x + xv.y * w0.y + xv.z * w0.z + xv.w * w0.w;
        aG += xv.x * w1.x + xv.y * w1.y + xv.z * w1.z + xv.w * w1.w;
        aO += xv.x * w2.x + xv.y * w2.y + xv.z * w2.z + xv.w * w2.w;
    }
    float i_ = sigm(aI + b1[1024 + tid]);
    float g_ = tanh_(aG + b1[1024 + 512 + tid]);
    float o_ = sigm(aO + b1[1024 + 768 + tid]);
    float c = i_ * g_;  // c0 = 0
    float hb = o_ * tanh_(c);
    float part = h1f[b * 256 + tid] * fcw[tid] + hb * fcw[256 + tid];
    red[tid] = part;
    __syncthreads();
    for (int sx = 128; sx > 0; sx >>= 1) {
        if (tid < sx) red[tid] += red[tid + sx];
        __syncthreads();
    }
    if (tid == 0) out[b] = red[0] + fcb[0];
}

extern "C" void kernel_launch(void* const* d_in, const int* in_sizes, int n_in,
                              void* d_out, int out_size, void* d_ws, size_t ws_size,
                              hipStream_t stream) {
    const float* x    = (const float*)d_in[0];
    const float* Wih0 = (const float*)d_in[1];
    const float* Whh0 = (const float*)d_in[2];
    const float* b0   = (const float*)d_in[3];
    const float* Wih1 = (const float*)d_in[4];
    const float* Whh1 = (const float*)d_in[5];
    const float* b1   = (const float*)d_in[6];
    const float* fcw  = (const float*)d_in[7];
    const float* fcb  = (const float*)d_in[8];

    char* ws = (char*)d_ws;
    _Float16* W0pack = (_Float16*)(ws + 0);          // 1,310,720 B
    _Float16* W1pack = (_Float16*)(ws + 1310720);    // 1,572,864 B -> 2,883,584
    u64* hbuf0       = (u64*)(ws + 2883584);         // 1,048,576 B -> 3,932,160
    u64* hbuf1       = (u64*)(ws + 3932160);         //   524,288 B -> 4,456,448
    float* h1f       = (float*)(ws + 4456448);       //   262,144 B -> 4,718,592
    _Float16* out0   = (_Float16*)(ws + 4718592);    // 134,217,728 B -> ~138.9 MB

    // poison both tag buffers (tag 0xFFFFFFFF != any step); replay-safe
    hipMemsetAsync(ws + 2883584, 0xFF, 1572864, stream);

    // L0: QW=32, NSUB=2, NQ=8, KT=10, dirs=2 -> 655360 elems
    hipLaunchKernelGGL(pack_w, dim3(2560), dim3(256), 0, stream,
                       Wih0, Whh0, W0pack, 64, 256, 10, 32, 2, 8, 655360);
    // L1: QW=16, NSUB=1, NQ=16, KT=24, dirs=1 -> 786432 elems
    hipLaunchKernelGGL(pack_w, dim3(3072), dim3(256), 0, stream,
                       Wih1, Whh1, W1pack, 512, 256, 24, 16, 1, 16, 786432);

    // L0 LDS: 81920(w) + 16896(h) + 4608(a) + 16896(g) = 120,320 -> 1 blk/CU
    hipFuncSetAttribute((const void*)(lstm_scan<2, 8, 32, 32, true>),
                        hipFuncAttributeMaxDynamicSharedMemorySize, 120320);
    // L1 LDS: 98304(w) + 8448(h) + 16640(a) + 4352(g) = 127,744 -> 1 blk/CU
    hipFuncSetAttribute((const void*)(lstm_scan<16, 8, 16, 16, false>),
                        hipFuncAttributeMaxDynamicSharedMemorySize, 127744);

    // L0: 16 groups (2 dir x 8 bg, M=32) x 8 col-blocks = 128 blocks
    hipLaunchKernelGGL((lstm_scan<2, 8, 32, 32, true>), dim3(128), dim3(512), 120320, stream,
                       x, (const _Float16*)nullptr, W0pack, b0, hbuf0,
                       out0, (float*)nullptr);
    // L1 fwd: 16 groups (M=16) x 16 col-blocks = 256 blocks, K=768 folded
    hipLaunchKernelGGL((lstm_scan<16, 8, 16, 16, false>), dim3(256), dim3(256), 127744, stream,
                       (const float*)nullptr, (const _Float16*)out0, W1pack, b1, hbuf1,
                       (_Float16*)nullptr, h1f);
    hipLaunchKernelGGL(tail_kernel, dim3(256), dim3(256), 0, stream,
                       out0, Wih1, b1, fcw, fcb, h1f, (float*)d_out);
}